// Round 13
// baseline (273.326 us; speedup 1.0000x reference)
//
#include <hip/hip_runtime.h>
#include <hip/hip_bf16.h>

typedef __attribute__((ext_vector_type(8))) short short8;
typedef __attribute__((ext_vector_type(4))) float floatx4;

#define NSEQ 16
#define SEQ 128
#define DIM 256
#define HID 256
#define K3H 768
#define K2D 512
#define LOG2E 1.442695041f
#define LOG2E2 2.885390082f

__device__ __forceinline__ float frcp(float x) { return __builtin_amdgcn_rcpf(x); }
__device__ __forceinline__ unsigned short bf16bits(float v) {
    unsigned u = __builtin_bit_cast(unsigned, v);
    unsigned r = (u + 0x7FFFu + ((u >> 16) & 1u)) >> 16;
    return (unsigned short)r;
}
// async global->LDS DMA, 16B/lane: LDS dest = uniform base + lane*16 (HW rule)
__device__ __forceinline__ void load_lds16(const float* gsrc, float* ldsbase) {
    __builtin_amdgcn_global_load_lds(
        (const __attribute__((address_space(1))) void*)gsrc,
        (__attribute__((address_space(3))) void*)ldsbase, 16, 0, 0);
}

// ---------------- K1: left = x@w1, right = x@w2  (8 rows/block, v1-proven) ----------------
// outputs prescaled by 2*log2e (k2 consumes via exp2-tanh)
__global__ __launch_bounds__(256) void k1_leftright(
        const float* __restrict__ x, const float* __restrict__ w1,
        const float* __restrict__ w2, float* __restrict__ left,
        float* __restrict__ right) {
    __shared__ __align__(16) float xs[8][DIM];
    const int tid = threadIdx.x;
    const int r0 = blockIdx.x * 8;
    #pragma unroll
    for (int i = 0; i < 8; ++i) xs[i][tid] = x[(r0 + i) * DIM + tid];
    __syncthreads();
    float accL[8], accR[8];
    #pragma unroll
    for (int i = 0; i < 8; ++i) { accL[i] = 0.f; accR[i] = 0.f; }
    #pragma unroll 4
    for (int d = 0; d < DIM; ++d) {
        float wa = w1[d * DIM + tid];
        float wb = w2[d * DIM + tid];
        #pragma unroll
        for (int i = 0; i < 8; ++i) {
            float xv = xs[i][d];
            accL[i] = fmaf(xv, wa, accL[i]);
            accR[i] = fmaf(xv, wb, accR[i]);
        }
    }
    #pragma unroll
    for (int i = 0; i < 8; ++i) {
        left[(r0 + i) * DIM + tid]  = accL[i] * LOG2E2;
        right[(r0 + i) * DIM + tid] = accR[i] * LOG2E2;
    }
}

// ---------------- K2 v2: 8 m-rows per block (round-10 proven) ----------------
__global__ __launch_bounds__(256) void k2_attn(
        const float* __restrict__ x, const float* __restrict__ left,
        const float* __restrict__ right, const float* __restrict__ bias,
        const float* __restrict__ v3, float* __restrict__ cout) {
    __shared__ __align__(16) float lm[8][DIM];
    __shared__ __align__(16) float v3s[DIM];
    __shared__ __align__(16) float P[8][SEQ];
    const int tid = threadIdx.x;
    const int b  = blockIdx.x >> 4;          // sequence
    const int m0 = (blockIdx.x & 15) * 8;    // first of 8 m-rows

    v3s[tid & 255] = v3[tid & 255];
    #pragma unroll
    for (int i = 0; i < 8; ++i)
        lm[i][tid] = left[(size_t)(b * SEQ + m0 + i) * DIM + tid] + bias[tid] * LOG2E2;
    __syncthreads();

    const int mi = tid >> 5;        // 0..7
    const int nl = tid & 31;        // 0..31
    float sacc[4] = {0.f, 0.f, 0.f, 0.f};
    const float4* lv4 = reinterpret_cast<const float4*>(lm[mi]);
    const float4* vv4 = reinterpret_cast<const float4*>(v3s);
    #pragma unroll 2
    for (int d4 = 0; d4 < DIM / 4; ++d4) {
        float4 lv = lv4[d4];
        float4 vv = vv4[d4];
        #pragma unroll
        for (int rep = 0; rep < 4; ++rep) {
            const int n = nl + rep * 32;
            float4 rv = reinterpret_cast<const float4*>(right + (size_t)(b * SEQ + n) * DIM)[d4];
            float t0 = 1.f - 2.f * frcp(1.f + __builtin_amdgcn_exp2f(lv.x + rv.x));
            float t1 = 1.f - 2.f * frcp(1.f + __builtin_amdgcn_exp2f(lv.y + rv.y));
            float t2 = 1.f - 2.f * frcp(1.f + __builtin_amdgcn_exp2f(lv.z + rv.z));
            float t3 = 1.f - 2.f * frcp(1.f + __builtin_amdgcn_exp2f(lv.w + rv.w));
            sacc[rep] = fmaf(t0, vv.x, sacc[rep]);
            sacc[rep] = fmaf(t1, vv.y, sacc[rep]);
            sacc[rep] = fmaf(t2, vv.z, sacc[rep]);
            sacc[rep] = fmaf(t3, vv.w, sacc[rep]);
        }
    }
    #pragma unroll
    for (int rep = 0; rep < 4; ++rep) P[mi][nl + rep * 32] = sacc[rep];
    __syncthreads();

    {
        const int w   = tid >> 6;
        const int lane = tid & 63;
        const int row = w * 2 + (lane >> 5);
        const int g   = lane & 31;
        float v0 = P[row][g], v1 = P[row][g + 32], v2 = P[row][g + 64], v3v = P[row][g + 96];
        float mx = fmaxf(fmaxf(v0, v1), fmaxf(v2, v3v));
        #pragma unroll
        for (int off = 16; off >= 1; off >>= 1) mx = fmaxf(mx, __shfl_xor(mx, off, 64));
        float e0 = __expf(v0 - mx), e1 = __expf(v1 - mx);
        float e2 = __expf(v2 - mx), e3 = __expf(v3v - mx);
        float sm = e0 + e1 + e2 + e3;
        #pragma unroll
        for (int off = 16; off >= 1; off >>= 1) sm += __shfl_xor(sm, off, 64);
        float inv = frcp(sm);
        P[row][g] = e0 * inv; P[row][g + 32] = e1 * inv;
        P[row][g + 64] = e2 * inv; P[row][g + 96] = e3 * inv;
    }
    __syncthreads();

    float acc[8];
    #pragma unroll
    for (int i = 0; i < 8; ++i) acc[i] = 0.f;
    const float* xb = x + (size_t)b * SEQ * DIM;
    for (int nc = 0; nc < SEQ / 4; ++nc) {
        float xv0 = xb[(nc * 4 + 0) * DIM + tid];
        float xv1 = xb[(nc * 4 + 1) * DIM + tid];
        float xv2 = xb[(nc * 4 + 2) * DIM + tid];
        float xv3 = xb[(nc * 4 + 3) * DIM + tid];
        #pragma unroll
        for (int i = 0; i < 8; ++i) {
            float4 pv = *reinterpret_cast<const float4*>(&P[i][nc * 4]);
            acc[i] = fmaf(pv.x, xv0, acc[i]);
            acc[i] = fmaf(pv.y, xv1, acc[i]);
            acc[i] = fmaf(pv.z, xv2, acc[i]);
            acc[i] = fmaf(pv.w, xv3, acc[i]);
        }
    }
    #pragma unroll
    for (int i = 0; i < 8; ++i)
        cout[(size_t)(b * SEQ + m0 + i) * DIM + tid] = acc[i];
}

// ---------------- K3 v2: bf16 MFMA GEMM (round-10 proven) ----------------
__global__ __launch_bounds__(512) void k3_mfma(
        const float* __restrict__ x, const float* __restrict__ c,
        const float* __restrict__ gk, const float* __restrict__ gbias,
        float* __restrict__ xp) {
    __shared__ __align__(16) unsigned short As[64][72];    // [m][k]
    __shared__ __align__(16) unsigned short Bs[192][72];   // [n][k] (transposed)
    const int tid  = threadIdx.x;
    const int lane = tid & 63;
    const int w    = tid >> 6;
    const int l15  = lane & 15;
    const int g4   = lane >> 4;
    const int wm   = w >> 2;          // 0..1
    const int wn   = w & 3;           // 0..3
    const int m0   = (blockIdx.x & 31) * 64;
    const int n0   = (blockIdx.x >> 5) * 192;

    floatx4 Cf[2][3];
    #pragma unroll
    for (int i = 0; i < 2; ++i)
        #pragma unroll
        for (int j = 0; j < 3; ++j) Cf[i][j] = (floatx4){0.f, 0.f, 0.f, 0.f};

    for (int ch = 0; ch < 8; ++ch) {
        const int kbase = ch * 64;
        #pragma unroll
        for (int q = 0; q < 2; ++q) {
            int fi = q * 512 + tid;
            int row = fi >> 4, kq = (fi & 15) << 2;
            int kg = kbase + kq;
            const float* src = (kg < 256) ? &x[(size_t)(m0 + row) * DIM + kg]
                                          : &c[(size_t)(m0 + row) * DIM + (kg - 256)];
            float4 v = *reinterpret_cast<const float4*>(src);
            unsigned short* dst = &As[row][kq];
            dst[0] = bf16bits(v.x); dst[1] = bf16bits(v.y);
            dst[2] = bf16bits(v.z); dst[3] = bf16bits(v.w);
        }
        #pragma unroll
        for (int q = 0; q < 6; ++q) {
            int fi = q * 512 + tid;
            int krow = fi / 48, nq = (fi % 48) << 2;
            float4 v = *reinterpret_cast<const float4*>(
                &gk[(size_t)(kbase + krow) * K3H + n0 + nq]);
            Bs[nq + 0][krow] = bf16bits(v.x);
            Bs[nq + 1][krow] = bf16bits(v.y);
            Bs[nq + 2][krow] = bf16bits(v.z);
            Bs[nq + 3][krow] = bf16bits(v.w);
        }
        __syncthreads();
        #pragma unroll
        for (int kk = 0; kk < 2; ++kk) {
            short8 af[2], bf[3];
            #pragma unroll
            for (int i = 0; i < 2; ++i)
                af[i] = *reinterpret_cast<const short8*>(&As[wm * 32 + i * 16 + l15][kk * 32 + g4 * 8]);
            #pragma unroll
            for (int j = 0; j < 3; ++j)
                bf[j] = *reinterpret_cast<const short8*>(&Bs[wn * 48 + j * 16 + l15][kk * 32 + g4 * 8]);
            #pragma unroll
            for (int i = 0; i < 2; ++i)
                #pragma unroll
                for (int j = 0; j < 3; ++j)
                    Cf[i][j] = __builtin_amdgcn_mfma_f32_16x16x32_bf16(af[i], bf[j], Cf[i][j], 0, 0, 0);
        }
        __syncthreads();
    }

    #pragma unroll
    for (int j = 0; j < 3; ++j) {
        const int nbase = n0 + wn * 48 + j * 16;
        const int col = nbase + l15;
        const float sc = (nbase >= 512) ? LOG2E2 : LOG2E;
        const float bv = ((col < 512) ? (gbias[col] + gbias[K3H + col]) : gbias[col]) * sc;
        #pragma unroll
        for (int i = 0; i < 2; ++i) {
            const int rbase = m0 + wm * 32 + i * 16 + g4 * 4;
            #pragma unroll
            for (int r = 0; r < 4; ++r)
                xp[(size_t)(rbase + r) * K3H + col] = fmaf(Cf[i][j][r], sc, bv);
        }
    }
}

// ---------------- K4 v12 = v11 step loop + DIRECT-GATHER weight preload ----------------
// Preload: each lane loads its 384 fragment elements straight from global
// (rec[k*768 + col], k = kc*32 + g4*8 + j — identical k-mapping and identical
// bf16 values to the staged version). Lanes l15=0..15 hit 16 consecutive floats
// (64B coalesced segments); 384 pipelined loads ≈ 3-5us vs ~15-25us for the
// 16-part staged pipeline (which had 32 barriers + strided LDS re-reads).
// Kills the 49KB ws buffer. Step loop byte-identical to v11 (proven 181us).
__global__ __launch_bounds__(512) void k4_gru(
        const float* __restrict__ rec, const float* __restrict__ gbias,
        const float* __restrict__ xp, float* __restrict__ out) {
    __shared__ __align__(16) float xq0[K3H], xq1[K3H], xq2[K3H];
    __shared__ __align__(16) unsigned short hbf[2][HID];  // 1KB dbuf h (bf16)
    const int tid  = threadIdx.x;
    const int lane = tid & 63;
    const int wv   = tid >> 6;     // 0..7
    const int seq  = blockIdx.x;   // 0..15
    const int l15  = lane & 15;
    const int g4   = lane >> 4;    // 0..3

    // ---- Direct-gather preload of prescaled bf16 B-fragments ----
    short8 Bf[6][8];
    #pragma unroll
    for (int u = 0; u < 6; ++u) {
        const float sc = (u >= 4) ? LOG2E2 : LOG2E;
        const int col = (u >> 1) * 256 + (u & 1) * 16 + wv * 32 + l15;
        const float* rc = rec + col;
        #pragma unroll
        for (int kc = 0; kc < 8; ++kc) {
            #pragma unroll
            for (int j = 0; j < 8; ++j) {
                const int k = kc * 32 + g4 * 8 + j;
                Bf[u][kc][j] = (short)bf16bits(rc[(size_t)k * K3H] * sc);
            }
        }
    }

    const int dd = wv * 32 + (lane & 31);
    const float brh_l = gbias[K3H + 512 + dd] * LOG2E2;
    const int tsel = (lane >> 4) & 1;

    const float* xps = xp + (size_t)seq * SEQ * K3H;
    float* outs = out + (size_t)seq * SEQ * HID;

    float h = 0.f;
    if (tid < HID) hbf[0][tid] = 0;

    // prologue: DMA rows 0 and 1; full drain once
    if (wv < 3) {
        load_lds16(xps + wv * 256 + (lane << 2),       xq0 + wv * 256);
        load_lds16(xps + K3H + wv * 256 + (lane << 2), xq1 + wv * 256);
    }
    asm volatile("s_waitcnt vmcnt(0)" ::: "memory");
    __syncthreads();

    // rotating xq pointers: p0 = read(s), p1 = read(s+1), p2 = DMA target (s+2)
    float* p0 = xq0;
    float* p1 = xq1;
    float* p2 = xq2;

    // one GRU step; CB/NB are compile-time via unroll-2
    #define K4_STEP(s_, CB, NB)                                                         \
    {                                                                                   \
        const int sp = ((s_) + 2 < SEQ) ? (s_) + 2 : SEQ - 1;                           \
        if (wv < 3)                                                                     \
            load_lds16(xps + (size_t)sp * K3H + wv * 256 + (lane << 2), p2 + wv * 256); \
        short8 av[8];                                                                   \
        _Pragma("unroll")                                                               \
        for (int kc = 0; kc < 8; ++kc)                                                  \
            av[kc] = *reinterpret_cast<const short8*>(&hbf[CB][kc * 32 + g4 * 8]);      \
        const float xz = p0[dd];                                                        \
        const float xr = p0[256 + dd];                                                  \
        const float xh = p0[512 + dd];                                                  \
        floatx4 C[6];                                                                   \
        _Pragma("unroll")                                                               \
        for (int u = 0; u < 6; ++u) C[u] = (floatx4){0.f, 0.f, 0.f, 0.f};               \
        _Pragma("unroll")                                                               \
        for (int kc = 0; kc < 8; ++kc) {                                                \
            _Pragma("unroll")                                                           \
            for (int u = 0; u < 6; ++u)                                                 \
                C[u] = __builtin_amdgcn_mfma_f32_16x16x32_bf16(av[kc], Bf[u][kc],       \
                                                               C[u], 0, 0, 0);         \
        }                                                                               \
        if (lane < 32) {                                                                \
            float rz = tsel ? C[1][0] : C[0][0];                                        \
            float rr = tsel ? C[3][0] : C[2][0];                                        \
            float rh = tsel ? C[5][0] : C[4][0];                                        \
            float z  = frcp(1.f + __builtin_amdgcn_exp2f(-(rz + xz)));                  \
            float r  = frcp(1.f + __builtin_amdgcn_exp2f(-(rr + xr)));                  \
            float th = fmaf(r, rh + brh_l, xh);                                         \
            float hh = 1.f - 2.f * frcp(1.f + __builtin_amdgcn_exp2f(th));              \
            h = hh + z * (h - hh);                                                      \
            hbf[NB][dd] = bf16bits(h);                                                  \
            outs[(s_) * HID + dd] = h;                                                  \
        }                                                                               \
        asm volatile("s_waitcnt vmcnt(3) lgkmcnt(0)\n\ts_barrier" ::: "memory");        \
        float* tmp_ = p0; p0 = p1; p1 = p2; p2 = tmp_;                                  \
    }

    for (int s = 0; s < SEQ; s += 2) {
        K4_STEP(s,     0, 1)
        K4_STEP(s + 1, 1, 0)
    }
    #undef K4_STEP
}

extern "C" void kernel_launch(void* const* d_in, const int* in_sizes, int n_in,
                              void* d_out, int out_size, void* d_ws, size_t ws_size,
                              hipStream_t stream) {
    const float* feat = (const float*)d_in[0];
    const float* w1   = (const float*)d_in[1];
    const float* w2   = (const float*)d_in[2];
    const float* bias = (const float*)d_in[3];
    const float* v3   = (const float*)d_in[4];
    const float* gk   = (const float*)d_in[5];
    const float* grk  = (const float*)d_in[6];
    const float* gb   = (const float*)d_in[7];
    float* out = (float*)d_out;

    char* wsb = (char*)d_ws;
    float* left  = (float*)(wsb);
    float* right = (float*)(wsb + (size_t)2 * 1024 * 1024);
    float* cbuf  = (float*)(wsb + (size_t)4 * 1024 * 1024);
    float* xp    = (float*)(wsb + (size_t)6 * 1024 * 1024);

    k1_leftright<<<2048 / 8, 256, 0, stream>>>(feat, w1, w2, left, right);
    k2_attn<<<NSEQ * 16, 256, 0, stream>>>(feat, left, right, bias, v3, cbuf);
    k3_mfma<<<128, 512, 0, stream>>>(feat, cbuf, gk, gb, xp);
    k4_gru<<<NSEQ, 512, 0, stream>>>(grk, gb, xp, out);
}

// Round 14
// 244.122 us; speedup vs baseline: 1.1196x; 1.1196x over previous
//
#include <hip/hip_runtime.h>
#include <hip/hip_bf16.h>

typedef __attribute__((ext_vector_type(8))) short short8;
typedef __attribute__((ext_vector_type(4))) float floatx4;

#define NSEQ 16
#define SEQ 128
#define DIM 256
#define HID 256
#define K3H 768
#define K2D 512
#define LOG2E 1.442695041f
#define LOG2E2 2.885390082f
#define WS_STRIDE 772   // 768 + 4: breaks 16-way preload bank conflict to 2-way (free)

__device__ __forceinline__ float frcp(float x) { return __builtin_amdgcn_rcpf(x); }
__device__ __forceinline__ unsigned short bf16bits(float v) {
    unsigned u = __builtin_bit_cast(unsigned, v);
    unsigned r = (u + 0x7FFFu + ((u >> 16) & 1u)) >> 16;
    return (unsigned short)r;
}
// async global->LDS DMA, 16B/lane: LDS dest = uniform base + lane*16 (HW rule)
__device__ __forceinline__ void load_lds16(const float* gsrc, float* ldsbase) {
    __builtin_amdgcn_global_load_lds(
        (const __attribute__((address_space(1))) void*)gsrc,
        (__attribute__((address_space(3))) void*)ldsbase, 16, 0, 0);
}

// ---------------- K1 v2: bf16 MFMA GEMM  left/right = x @ {w1,w2} ----------------
// M=2048, N=256, K=256. 64 blocks = 32 m-tiles x {left,right}. 512 thr, block tile
// 64m x 256n, wave (wm=w>>2, wn=w&3) tile 32m x 64n = 2x4 frags. K chunks of 32.
// Same staging + fragment mapping as k3_mfma (proven). Outputs prescaled by 2log2e.
__global__ __launch_bounds__(512) void k1_mfma(
        const float* __restrict__ x, const float* __restrict__ w1,
        const float* __restrict__ w2, float* __restrict__ left,
        float* __restrict__ right) {
    __shared__ __align__(16) unsigned short As[64][40];    // [m][k], 80B rows (16B-mult)
    __shared__ __align__(16) unsigned short Bs[256][40];   // [n][k] (transposed)
    const int tid  = threadIdx.x;
    const int lane = tid & 63;
    const int w    = tid >> 6;
    const int l15  = lane & 15;
    const int g4   = lane >> 4;
    const int wm   = w >> 2;          // 0..1
    const int wn   = w & 3;           // 0..3
    const int m0   = (blockIdx.x >> 1) * 64;
    const float* B = (blockIdx.x & 1) ? w2 : w1;
    float* outp    = (blockIdx.x & 1) ? right : left;

    floatx4 Cf[2][4];
    #pragma unroll
    for (int i = 0; i < 2; ++i)
        #pragma unroll
        for (int j = 0; j < 4; ++j) Cf[i][j] = (floatx4){0.f, 0.f, 0.f, 0.f};

    for (int ch = 0; ch < 8; ++ch) {
        const int kbase = ch * 32;
        // stage A: 64m x 32k (512 float4, 1/thread); 8 thr/row, coalesced
        {
            int row = tid >> 3, kq = (tid & 7) << 2;
            float4 v = *reinterpret_cast<const float4*>(&x[(size_t)(m0 + row) * DIM + kbase + kq]);
            unsigned short* dst = &As[row][kq];
            dst[0] = bf16bits(v.x); dst[1] = bf16bits(v.y);
            dst[2] = bf16bits(v.z); dst[3] = bf16bits(v.w);
        }
        // stage B: 32k x 256n (2048 float4, 4/thread), transposed into Bs[n][k]
        #pragma unroll
        for (int q = 0; q < 4; ++q) {
            int fi = q * 512 + tid;
            int krow = fi >> 6, nq = (fi & 63) << 2;
            float4 v = *reinterpret_cast<const float4*>(&B[(size_t)(kbase + krow) * DIM + nq]);
            Bs[nq + 0][krow] = bf16bits(v.x);
            Bs[nq + 1][krow] = bf16bits(v.y);
            Bs[nq + 2][krow] = bf16bits(v.z);
            Bs[nq + 3][krow] = bf16bits(v.w);
        }
        __syncthreads();
        short8 af[2], bf[4];
        #pragma unroll
        for (int i = 0; i < 2; ++i)
            af[i] = *reinterpret_cast<const short8*>(&As[wm * 32 + i * 16 + l15][g4 * 8]);
        #pragma unroll
        for (int j = 0; j < 4; ++j)
            bf[j] = *reinterpret_cast<const short8*>(&Bs[wn * 64 + j * 16 + l15][g4 * 8]);
        #pragma unroll
        for (int i = 0; i < 2; ++i)
            #pragma unroll
            for (int j = 0; j < 4; ++j)
                Cf[i][j] = __builtin_amdgcn_mfma_f32_16x16x32_bf16(af[i], bf[j], Cf[i][j], 0, 0, 0);
        __syncthreads();
    }

    #pragma unroll
    for (int j = 0; j < 4; ++j) {
        const int col = wn * 64 + j * 16 + l15;
        #pragma unroll
        for (int i = 0; i < 2; ++i) {
            const int rbase = m0 + wm * 32 + i * 16 + g4 * 4;
            #pragma unroll
            for (int r = 0; r < 4; ++r)
                outp[(size_t)(rbase + r) * DIM + col] = Cf[i][j][r] * LOG2E2;
        }
    }
}

// ---------------- K2 v2: 8 m-rows per block (round-10 proven) ----------------
__global__ __launch_bounds__(256) void k2_attn(
        const float* __restrict__ x, const float* __restrict__ left,
        const float* __restrict__ right, const float* __restrict__ bias,
        const float* __restrict__ v3, float* __restrict__ cout) {
    __shared__ __align__(16) float lm[8][DIM];
    __shared__ __align__(16) float v3s[DIM];
    __shared__ __align__(16) float P[8][SEQ];
    const int tid = threadIdx.x;
    const int b  = blockIdx.x >> 4;          // sequence
    const int m0 = (blockIdx.x & 15) * 8;    // first of 8 m-rows

    v3s[tid & 255] = v3[tid & 255];
    #pragma unroll
    for (int i = 0; i < 8; ++i)
        lm[i][tid] = left[(size_t)(b * SEQ + m0 + i) * DIM + tid] + bias[tid] * LOG2E2;
    __syncthreads();

    const int mi = tid >> 5;        // 0..7
    const int nl = tid & 31;        // 0..31
    float sacc[4] = {0.f, 0.f, 0.f, 0.f};
    const float4* lv4 = reinterpret_cast<const float4*>(lm[mi]);
    const float4* vv4 = reinterpret_cast<const float4*>(v3s);
    #pragma unroll 2
    for (int d4 = 0; d4 < DIM / 4; ++d4) {
        float4 lv = lv4[d4];
        float4 vv = vv4[d4];
        #pragma unroll
        for (int rep = 0; rep < 4; ++rep) {
            const int n = nl + rep * 32;
            float4 rv = reinterpret_cast<const float4*>(right + (size_t)(b * SEQ + n) * DIM)[d4];
            float t0 = 1.f - 2.f * frcp(1.f + __builtin_amdgcn_exp2f(lv.x + rv.x));
            float t1 = 1.f - 2.f * frcp(1.f + __builtin_amdgcn_exp2f(lv.y + rv.y));
            float t2 = 1.f - 2.f * frcp(1.f + __builtin_amdgcn_exp2f(lv.z + rv.z));
            float t3 = 1.f - 2.f * frcp(1.f + __builtin_amdgcn_exp2f(lv.w + rv.w));
            sacc[rep] = fmaf(t0, vv.x, sacc[rep]);
            sacc[rep] = fmaf(t1, vv.y, sacc[rep]);
            sacc[rep] = fmaf(t2, vv.z, sacc[rep]);
            sacc[rep] = fmaf(t3, vv.w, sacc[rep]);
        }
    }
    #pragma unroll
    for (int rep = 0; rep < 4; ++rep) P[mi][nl + rep * 32] = sacc[rep];
    __syncthreads();

    {
        const int w   = tid >> 6;
        const int lane = tid & 63;
        const int row = w * 2 + (lane >> 5);
        const int g   = lane & 31;
        float v0 = P[row][g], v1 = P[row][g + 32], v2 = P[row][g + 64], v3v = P[row][g + 96];
        float mx = fmaxf(fmaxf(v0, v1), fmaxf(v2, v3v));
        #pragma unroll
        for (int off = 16; off >= 1; off >>= 1) mx = fmaxf(mx, __shfl_xor(mx, off, 64));
        float e0 = __expf(v0 - mx), e1 = __expf(v1 - mx);
        float e2 = __expf(v2 - mx), e3 = __expf(v3v - mx);
        float sm = e0 + e1 + e2 + e3;
        #pragma unroll
        for (int off = 16; off >= 1; off >>= 1) sm += __shfl_xor(sm, off, 64);
        float inv = frcp(sm);
        P[row][g] = e0 * inv; P[row][g + 32] = e1 * inv;
        P[row][g + 64] = e2 * inv; P[row][g + 96] = e3 * inv;
    }
    __syncthreads();

    float acc[8];
    #pragma unroll
    for (int i = 0; i < 8; ++i) acc[i] = 0.f;
    const float* xb = x + (size_t)b * SEQ * DIM;
    for (int nc = 0; nc < SEQ / 4; ++nc) {
        float xv0 = xb[(nc * 4 + 0) * DIM + tid];
        float xv1 = xb[(nc * 4 + 1) * DIM + tid];
        float xv2 = xb[(nc * 4 + 2) * DIM + tid];
        float xv3 = xb[(nc * 4 + 3) * DIM + tid];
        #pragma unroll
        for (int i = 0; i < 8; ++i) {
            float4 pv = *reinterpret_cast<const float4*>(&P[i][nc * 4]);
            acc[i] = fmaf(pv.x, xv0, acc[i]);
            acc[i] = fmaf(pv.y, xv1, acc[i]);
            acc[i] = fmaf(pv.z, xv2, acc[i]);
            acc[i] = fmaf(pv.w, xv3, acc[i]);
        }
    }
    #pragma unroll
    for (int i = 0; i < 8; ++i)
        cout[(size_t)(b * SEQ + m0 + i) * DIM + tid] = acc[i];
}

// ---------------- K3 v2: bf16 MFMA GEMM (round-10 proven) ----------------
__global__ __launch_bounds__(512) void k3_mfma(
        const float* __restrict__ x, const float* __restrict__ c,
        const float* __restrict__ gk, const float* __restrict__ gbias,
        float* __restrict__ xp) {
    __shared__ __align__(16) unsigned short As[64][72];    // [m][k]
    __shared__ __align__(16) unsigned short Bs[192][72];   // [n][k] (transposed)
    const int tid  = threadIdx.x;
    const int lane = tid & 63;
    const int w    = tid >> 6;
    const int l15  = lane & 15;
    const int g4   = lane >> 4;
    const int wm   = w >> 2;          // 0..1
    const int wn   = w & 3;           // 0..3
    const int m0   = (blockIdx.x & 31) * 64;
    const int n0   = (blockIdx.x >> 5) * 192;

    floatx4 Cf[2][3];
    #pragma unroll
    for (int i = 0; i < 2; ++i)
        #pragma unroll
        for (int j = 0; j < 3; ++j) Cf[i][j] = (floatx4){0.f, 0.f, 0.f, 0.f};

    for (int ch = 0; ch < 8; ++ch) {
        const int kbase = ch * 64;
        #pragma unroll
        for (int q = 0; q < 2; ++q) {
            int fi = q * 512 + tid;
            int row = fi >> 4, kq = (fi & 15) << 2;
            int kg = kbase + kq;
            const float* src = (kg < 256) ? &x[(size_t)(m0 + row) * DIM + kg]
                                          : &c[(size_t)(m0 + row) * DIM + (kg - 256)];
            float4 v = *reinterpret_cast<const float4*>(src);
            unsigned short* dst = &As[row][kq];
            dst[0] = bf16bits(v.x); dst[1] = bf16bits(v.y);
            dst[2] = bf16bits(v.z); dst[3] = bf16bits(v.w);
        }
        #pragma unroll
        for (int q = 0; q < 6; ++q) {
            int fi = q * 512 + tid;
            int krow = fi / 48, nq = (fi % 48) << 2;
            float4 v = *reinterpret_cast<const float4*>(
                &gk[(size_t)(kbase + krow) * K3H + n0 + nq]);
            Bs[nq + 0][krow] = bf16bits(v.x);
            Bs[nq + 1][krow] = bf16bits(v.y);
            Bs[nq + 2][krow] = bf16bits(v.z);
            Bs[nq + 3][krow] = bf16bits(v.w);
        }
        __syncthreads();
        #pragma unroll
        for (int kk = 0; kk < 2; ++kk) {
            short8 af[2], bf[3];
            #pragma unroll
            for (int i = 0; i < 2; ++i)
                af[i] = *reinterpret_cast<const short8*>(&As[wm * 32 + i * 16 + l15][kk * 32 + g4 * 8]);
            #pragma unroll
            for (int j = 0; j < 3; ++j)
                bf[j] = *reinterpret_cast<const short8*>(&Bs[wn * 48 + j * 16 + l15][kk * 32 + g4 * 8]);
            #pragma unroll
            for (int i = 0; i < 2; ++i)
                #pragma unroll
                for (int j = 0; j < 3; ++j)
                    Cf[i][j] = __builtin_amdgcn_mfma_f32_16x16x32_bf16(af[i], bf[j], Cf[i][j], 0, 0, 0);
        }
        __syncthreads();
    }

    #pragma unroll
    for (int j = 0; j < 3; ++j) {
        const int nbase = n0 + wn * 48 + j * 16;
        const int col = nbase + l15;
        const float sc = (nbase >= 512) ? LOG2E2 : LOG2E;
        const float bv = ((col < 512) ? (gbias[col] + gbias[K3H + col]) : gbias[col]) * sc;
        #pragma unroll
        for (int i = 0; i < 2; ++i) {
            const int rbase = m0 + wm * 32 + i * 16 + g4 * 4;
            #pragma unroll
            for (int r = 0; r < 4; ++r)
                xp[(size_t)(rbase + r) * K3H + col] = fmaf(Cf[i][j][r], sc, bv);
        }
    }
}

// ---------------- K4 v11 (round-12 champion, 181us): staged preload + unroll-2 step ----------------
__global__ __launch_bounds__(512) void k4_gru(
        const float* __restrict__ rec, const float* __restrict__ gbias,
        const float* __restrict__ xp, float* __restrict__ out) {
    __shared__ __align__(16) float ws[16 * WS_STRIDE];    // 49.4KB preload staging
    __shared__ __align__(16) float xq0[K3H], xq1[K3H], xq2[K3H];
    __shared__ __align__(16) unsigned short hbf[2][HID];  // 1KB dbuf h (bf16)
    const int tid  = threadIdx.x;
    const int lane = tid & 63;
    const int wv   = tid >> 6;     // 0..7
    const int seq  = blockIdx.x;   // 0..15
    const int l15  = lane & 15;
    const int g4   = lane >> 4;    // 0..3

    // ---- Preload rec_kernel as prescaled bf16 B-fragments (staged, proven) ----
    short8 Bf[6][8];
    #pragma unroll
    for (int part = 0; part < 16; ++part) {
        #pragma unroll
        for (int q = 0; q < 6; ++q) {
            int fi = q * 512 + tid;
            int row = fi / 192, c4 = fi % 192;
            reinterpret_cast<float4*>(ws)[row * (WS_STRIDE / 4) + c4] =
                reinterpret_cast<const float4*>(rec + part * 16 * K3H)[fi];
        }
        __syncthreads();
        const int kc = part >> 1, half = part & 1;
        #pragma unroll
        for (int u = 0; u < 6; ++u) {
            const float sc = (u >= 4) ? LOG2E2 : LOG2E;
            const int col = (u >> 1) * 256 + (u & 1) * 16 + wv * 32 + l15;
            #pragma unroll
            for (int j = 0; j < 8; ++j) {
                int r = g4 * 8 + j;
                if ((r >> 4) == half)
                    Bf[u][kc][j] = (short)bf16bits(ws[(r & 15) * WS_STRIDE + col] * sc);
            }
        }
        __syncthreads();
    }

    const int dd = wv * 32 + (lane & 31);
    const float brh_l = gbias[K3H + 512 + dd] * LOG2E2;
    const int tsel = (lane >> 4) & 1;

    const float* xps = xp + (size_t)seq * SEQ * K3H;
    float* outs = out + (size_t)seq * SEQ * HID;

    float h = 0.f;
    if (tid < HID) hbf[0][tid] = 0;

    // prologue: DMA rows 0 and 1; full drain once
    if (wv < 3) {
        load_lds16(xps + wv * 256 + (lane << 2),       xq0 + wv * 256);
        load_lds16(xps + K3H + wv * 256 + (lane << 2), xq1 + wv * 256);
    }
    asm volatile("s_waitcnt vmcnt(0)" ::: "memory");
    __syncthreads();

    // rotating xq pointers: p0 = read(s), p1 = read(s+1), p2 = DMA target (s+2)
    float* p0 = xq0;
    float* p1 = xq1;
    float* p2 = xq2;

    // one GRU step; CB/NB are compile-time via unroll-2
    #define K4_STEP(s_, CB, NB)                                                         \
    {                                                                                   \
        const int sp = ((s_) + 2 < SEQ) ? (s_) + 2 : SEQ - 1;                           \
        if (wv < 3)                                                                     \
            load_lds16(xps + (size_t)sp * K3H + wv * 256 + (lane << 2), p2 + wv * 256); \
        short8 av[8];                                                                   \
        _Pragma("unroll")                                                               \
        for (int kc = 0; kc < 8; ++kc)                                                  \
            av[kc] = *reinterpret_cast<const short8*>(&hbf[CB][kc * 32 + g4 * 8]);      \
        const float xz = p0[dd];                                                        \
        const float xr = p0[256 + dd];                                                  \
        const float xh = p0[512 + dd];                                                  \
        floatx4 C[6];                                                                   \
        _Pragma("unroll")                                                               \
        for (int u = 0; u < 6; ++u) C[u] = (floatx4){0.f, 0.f, 0.f, 0.f};               \
        _Pragma("unroll")                                                               \
        for (int kc = 0; kc < 8; ++kc) {                                                \
            _Pragma("unroll")                                                           \
            for (int u = 0; u < 6; ++u)                                                 \
                C[u] = __builtin_amdgcn_mfma_f32_16x16x32_bf16(av[kc], Bf[u][kc],       \
                                                               C[u], 0, 0, 0);         \
        }                                                                               \
        if (lane < 32) {                                                                \
            float rz = tsel ? C[1][0] : C[0][0];                                        \
            float rr = tsel ? C[3][0] : C[2][0];                                        \
            float rh = tsel ? C[5][0] : C[4][0];                                        \
            float z  = frcp(1.f + __builtin_amdgcn_exp2f(-(rz + xz)));                  \
            float r  = frcp(1.f + __builtin_amdgcn_exp2f(-(rr + xr)));                  \
            float th = fmaf(r, rh + brh_l, xh);                                         \
            float hh = 1.f - 2.f * frcp(1.f + __builtin_amdgcn_exp2f(th));              \
            h = hh + z * (h - hh);                                                      \
            hbf[NB][dd] = bf16bits(h);                                                  \
            outs[(s_) * HID + dd] = h;                                                  \
        }                                                                               \
        asm volatile("s_waitcnt vmcnt(3) lgkmcnt(0)\n\ts_barrier" ::: "memory");        \
        float* tmp_ = p0; p0 = p1; p1 = p2; p2 = tmp_;                                  \
    }

    for (int s = 0; s < SEQ; s += 2) {
        K4_STEP(s,     0, 1)
        K4_STEP(s + 1, 1, 0)
    }
    #undef K4_STEP
}

extern "C" void kernel_launch(void* const* d_in, const int* in_sizes, int n_in,
                              void* d_out, int out_size, void* d_ws, size_t ws_size,
                              hipStream_t stream) {
    const float* feat = (const float*)d_in[0];
    const float* w1   = (const float*)d_in[1];
    const float* w2   = (const float*)d_in[2];
    const float* bias = (const float*)d_in[3];
    const float* v3   = (const float*)d_in[4];
    const float* gk   = (const float*)d_in[5];
    const float* grk  = (const float*)d_in[6];
    const float* gb   = (const float*)d_in[7];
    float* out = (float*)d_out;

    char* wsb = (char*)d_ws;
    float* left  = (float*)(wsb);
    float* right = (float*)(wsb + (size_t)2 * 1024 * 1024);
    float* cbuf  = (float*)(wsb + (size_t)4 * 1024 * 1024);
    float* xp    = (float*)(wsb + (size_t)6 * 1024 * 1024);

    k1_mfma<<<64, 512, 0, stream>>>(feat, w1, w2, left, right);
    k2_attn<<<NSEQ * 16, 256, 0, stream>>>(feat, left, right, bias, v3, cbuf);
    k3_mfma<<<128, 512, 0, stream>>>(feat, cbuf, gk, gb, xp);
    k4_gru<<<NSEQ, 512, 0, stream>>>(grk, gb, xp, out);
}

// Round 15
// 238.130 us; speedup vs baseline: 1.1478x; 1.0252x over previous
//
#include <hip/hip_runtime.h>
#include <hip/hip_bf16.h>

typedef __attribute__((ext_vector_type(8))) short short8;
typedef __attribute__((ext_vector_type(4))) float floatx4;

#define NSEQ 16
#define SEQ 128
#define DIM 256
#define HID 256
#define K3H 768
#define K2D 512
#define LOG2E 1.442695041f
#define LOG2E2 2.885390082f
#define WS_STRIDE 772   // 768 + 4: breaks 16-way preload bank conflict to 2-way (free)

__device__ __forceinline__ float frcp(float x) { return __builtin_amdgcn_rcpf(x); }
__device__ __forceinline__ unsigned short bf16bits(float v) {
    unsigned u = __builtin_bit_cast(unsigned, v);
    unsigned r = (u + 0x7FFFu + ((u >> 16) & 1u)) >> 16;
    return (unsigned short)r;
}
// async global->LDS DMA, 16B/lane: LDS dest = uniform base + lane*16 (HW rule)
__device__ __forceinline__ void load_lds16(const float* gsrc, float* ldsbase) {
    __builtin_amdgcn_global_load_lds(
        (const __attribute__((address_space(1))) void*)gsrc,
        (__attribute__((address_space(3))) void*)ldsbase, 16, 0, 0);
}

// ---------------- K1: left = x@w1, right = x@w2  (8 rows/block, round-12 proven) ----------------
// outputs prescaled by 2*log2e (k2 consumes via exp2-tanh)
__global__ __launch_bounds__(256) void k1_leftright(
        const float* __restrict__ x, const float* __restrict__ w1,
        const float* __restrict__ w2, float* __restrict__ left,
        float* __restrict__ right) {
    __shared__ __align__(16) float xs[8][DIM];
    const int tid = threadIdx.x;
    const int r0 = blockIdx.x * 8;
    #pragma unroll
    for (int i = 0; i < 8; ++i) xs[i][tid] = x[(r0 + i) * DIM + tid];
    __syncthreads();
    float accL[8], accR[8];
    #pragma unroll
    for (int i = 0; i < 8; ++i) { accL[i] = 0.f; accR[i] = 0.f; }
    #pragma unroll 4
    for (int d = 0; d < DIM; ++d) {
        float wa = w1[d * DIM + tid];
        float wb = w2[d * DIM + tid];
        #pragma unroll
        for (int i = 0; i < 8; ++i) {
            float xv = xs[i][d];
            accL[i] = fmaf(xv, wa, accL[i]);
            accR[i] = fmaf(xv, wb, accR[i]);
        }
    }
    #pragma unroll
    for (int i = 0; i < 8; ++i) {
        left[(r0 + i) * DIM + tid]  = accL[i] * LOG2E2;
        right[(r0 + i) * DIM + tid] = accR[i] * LOG2E2;
    }
}

// ---------------- K2 v3: 4 m-rows per block, 512 blocks (2/CU), register softmax ----------------
// One wave per m-row: scores stay in the wave's registers through softmax
// (shuffle-reduce over 64 lanes, 2 reps), P written to LDS once for the c-phase.
// One barrier fewer and 2x occupancy vs the round-10 version.
__global__ __launch_bounds__(256) void k2_attn(
        const float* __restrict__ x, const float* __restrict__ left,
        const float* __restrict__ right, const float* __restrict__ bias,
        const float* __restrict__ v3, float* __restrict__ cout) {
    __shared__ __align__(16) float lm[4][DIM];
    __shared__ __align__(16) float v3s[DIM];
    __shared__ __align__(16) float P[4][SEQ];
    const int tid = threadIdx.x;
    const int b  = blockIdx.x >> 5;          // sequence
    const int m0 = (blockIdx.x & 31) * 4;    // first of 4 m-rows

    v3s[tid] = v3[tid];
    #pragma unroll
    for (int i = 0; i < 4; ++i)
        lm[i][tid] = left[(size_t)(b * SEQ + m0 + i) * DIM + tid] + bias[tid] * LOG2E2;
    __syncthreads();

    // ---- scores: wave mi owns row m0+mi; lane nl covers n = nl, nl+64 ----
    const int mi = tid >> 6;        // 0..3 (wave)
    const int nl = tid & 63;        // lane
    float s0 = 0.f, s1 = 0.f;
    const float4* lv4 = reinterpret_cast<const float4*>(lm[mi]);
    const float4* vv4 = reinterpret_cast<const float4*>(v3s);
    const float4* r0v = reinterpret_cast<const float4*>(right + (size_t)(b * SEQ + nl) * DIM);
    const float4* r1v = reinterpret_cast<const float4*>(right + (size_t)(b * SEQ + nl + 64) * DIM);
    #pragma unroll 2
    for (int d4 = 0; d4 < DIM / 4; ++d4) {
        float4 lv = lv4[d4];
        float4 vv = vv4[d4];
        float4 ra = r0v[d4];
        float4 rb = r1v[d4];
        float a0 = 1.f - 2.f * frcp(1.f + __builtin_amdgcn_exp2f(lv.x + ra.x));
        float a1 = 1.f - 2.f * frcp(1.f + __builtin_amdgcn_exp2f(lv.y + ra.y));
        float a2 = 1.f - 2.f * frcp(1.f + __builtin_amdgcn_exp2f(lv.z + ra.z));
        float a3 = 1.f - 2.f * frcp(1.f + __builtin_amdgcn_exp2f(lv.w + ra.w));
        s0 = fmaf(a0, vv.x, s0); s0 = fmaf(a1, vv.y, s0);
        s0 = fmaf(a2, vv.z, s0); s0 = fmaf(a3, vv.w, s0);
        float b0 = 1.f - 2.f * frcp(1.f + __builtin_amdgcn_exp2f(lv.x + rb.x));
        float b1 = 1.f - 2.f * frcp(1.f + __builtin_amdgcn_exp2f(lv.y + rb.y));
        float b2 = 1.f - 2.f * frcp(1.f + __builtin_amdgcn_exp2f(lv.z + rb.z));
        float b3 = 1.f - 2.f * frcp(1.f + __builtin_amdgcn_exp2f(lv.w + rb.w));
        s1 = fmaf(b0, vv.x, s1); s1 = fmaf(b1, vv.y, s1);
        s1 = fmaf(b2, vv.z, s1); s1 = fmaf(b3, vv.w, s1);
    }
    // ---- softmax in registers (wave-wide shuffle reduce) ----
    float mx = fmaxf(s0, s1);
    #pragma unroll
    for (int off = 32; off >= 1; off >>= 1) mx = fmaxf(mx, __shfl_xor(mx, off, 64));
    float e0 = __expf(s0 - mx), e1 = __expf(s1 - mx);
    float sm = e0 + e1;
    #pragma unroll
    for (int off = 32; off >= 1; off >>= 1) sm += __shfl_xor(sm, off, 64);
    float inv = frcp(sm);
    P[mi][nl]      = e0 * inv;
    P[mi][nl + 64] = e1 * inv;
    __syncthreads();

    // ---- c[m0+i][d] = sum_n P[i][n] x[b,n,d]; thread = d ----
    float acc[4] = {0.f, 0.f, 0.f, 0.f};
    const float* xb = x + (size_t)b * SEQ * DIM;
    for (int nc = 0; nc < SEQ / 4; ++nc) {
        float xv0 = xb[(nc * 4 + 0) * DIM + tid];
        float xv1 = xb[(nc * 4 + 1) * DIM + tid];
        float xv2 = xb[(nc * 4 + 2) * DIM + tid];
        float xv3 = xb[(nc * 4 + 3) * DIM + tid];
        #pragma unroll
        for (int i = 0; i < 4; ++i) {
            float4 pv = *reinterpret_cast<const float4*>(&P[i][nc * 4]);
            acc[i] = fmaf(pv.x, xv0, acc[i]);
            acc[i] = fmaf(pv.y, xv1, acc[i]);
            acc[i] = fmaf(pv.z, xv2, acc[i]);
            acc[i] = fmaf(pv.w, xv3, acc[i]);
        }
    }
    #pragma unroll
    for (int i = 0; i < 4; ++i)
        cout[(size_t)(b * SEQ + m0 + i) * DIM + tid] = acc[i];
}

// ---------------- K3 v2: bf16 MFMA GEMM (round-10 proven) ----------------
__global__ __launch_bounds__(512) void k3_mfma(
        const float* __restrict__ x, const float* __restrict__ c,
        const float* __restrict__ gk, const float* __restrict__ gbias,
        float* __restrict__ xp) {
    __shared__ __align__(16) unsigned short As[64][72];    // [m][k]
    __shared__ __align__(16) unsigned short Bs[192][72];   // [n][k] (transposed)
    const int tid  = threadIdx.x;
    const int lane = tid & 63;
    const int w    = tid >> 6;
    const int l15  = lane & 15;
    const int g4   = lane >> 4;
    const int wm   = w >> 2;          // 0..1
    const int wn   = w & 3;           // 0..3
    const int m0   = (blockIdx.x & 31) * 64;
    const int n0   = (blockIdx.x >> 5) * 192;

    floatx4 Cf[2][3];
    #pragma unroll
    for (int i = 0; i < 2; ++i)
        #pragma unroll
        for (int j = 0; j < 3; ++j) Cf[i][j] = (floatx4){0.f, 0.f, 0.f, 0.f};

    for (int ch = 0; ch < 8; ++ch) {
        const int kbase = ch * 64;
        #pragma unroll
        for (int q = 0; q < 2; ++q) {
            int fi = q * 512 + tid;
            int row = fi >> 4, kq = (fi & 15) << 2;
            int kg = kbase + kq;
            const float* src = (kg < 256) ? &x[(size_t)(m0 + row) * DIM + kg]
                                          : &c[(size_t)(m0 + row) * DIM + (kg - 256)];
            float4 v = *reinterpret_cast<const float4*>(src);
            unsigned short* dst = &As[row][kq];
            dst[0] = bf16bits(v.x); dst[1] = bf16bits(v.y);
            dst[2] = bf16bits(v.z); dst[3] = bf16bits(v.w);
        }
        #pragma unroll
        for (int q = 0; q < 6; ++q) {
            int fi = q * 512 + tid;
            int krow = fi / 48, nq = (fi % 48) << 2;
            float4 v = *reinterpret_cast<const float4*>(
                &gk[(size_t)(kbase + krow) * K3H + n0 + nq]);
            Bs[nq + 0][krow] = bf16bits(v.x);
            Bs[nq + 1][krow] = bf16bits(v.y);
            Bs[nq + 2][krow] = bf16bits(v.z);
            Bs[nq + 3][krow] = bf16bits(v.w);
        }
        __syncthreads();
        #pragma unroll
        for (int kk = 0; kk < 2; ++kk) {
            short8 af[2], bf[3];
            #pragma unroll
            for (int i = 0; i < 2; ++i)
                af[i] = *reinterpret_cast<const short8*>(&As[wm * 32 + i * 16 + l15][kk * 32 + g4 * 8]);
            #pragma unroll
            for (int j = 0; j < 3; ++j)
                bf[j] = *reinterpret_cast<const short8*>(&Bs[wn * 48 + j * 16 + l15][kk * 32 + g4 * 8]);
            #pragma unroll
            for (int i = 0; i < 2; ++i)
                #pragma unroll
                for (int j = 0; j < 3; ++j)
                    Cf[i][j] = __builtin_amdgcn_mfma_f32_16x16x32_bf16(af[i], bf[j], Cf[i][j], 0, 0, 0);
        }
        __syncthreads();
    }

    #pragma unroll
    for (int j = 0; j < 3; ++j) {
        const int nbase = n0 + wn * 48 + j * 16;
        const int col = nbase + l15;
        const float sc = (nbase >= 512) ? LOG2E2 : LOG2E;
        const float bv = ((col < 512) ? (gbias[col] + gbias[K3H + col]) : gbias[col]) * sc;
        #pragma unroll
        for (int i = 0; i < 2; ++i) {
            const int rbase = m0 + wm * 32 + i * 16 + g4 * 4;
            #pragma unroll
            for (int r = 0; r < 4; ++r)
                xp[(size_t)(rbase + r) * K3H + col] = fmaf(Cf[i][j][r], sc, bv);
        }
    }
}

// ---------------- K4 v11 (round-12 champion, 181us): staged preload + unroll-2 step ----------------
__global__ __launch_bounds__(512) void k4_gru(
        const float* __restrict__ rec, const float* __restrict__ gbias,
        const float* __restrict__ xp, float* __restrict__ out) {
    __shared__ __align__(16) float ws[16 * WS_STRIDE];    // 49.4KB preload staging
    __shared__ __align__(16) float xq0[K3H], xq1[K3H], xq2[K3H];
    __shared__ __align__(16) unsigned short hbf[2][HID];  // 1KB dbuf h (bf16)
    const int tid  = threadIdx.x;
    const int lane = tid & 63;
    const int wv   = tid >> 6;     // 0..7
    const int seq  = blockIdx.x;   // 0..15
    const int l15  = lane & 15;
    const int g4   = lane >> 4;    // 0..3

    // ---- Preload rec_kernel as prescaled bf16 B-fragments (staged, proven) ----
    short8 Bf[6][8];
    #pragma unroll
    for (int part = 0; part < 16; ++part) {
        #pragma unroll
        for (int q = 0; q < 6; ++q) {
            int fi = q * 512 + tid;
            int row = fi / 192, c4 = fi % 192;
            reinterpret_cast<float4*>(ws)[row * (WS_STRIDE / 4) + c4] =
                reinterpret_cast<const float4*>(rec + part * 16 * K3H)[fi];
        }
        __syncthreads();
        const int kc = part >> 1, half = part & 1;
        #pragma unroll
        for (int u = 0; u < 6; ++u) {
            const float sc = (u >= 4) ? LOG2E2 : LOG2E;
            const int col = (u >> 1) * 256 + (u & 1) * 16 + wv * 32 + l15;
            #pragma unroll
            for (int j = 0; j < 8; ++j) {
                int r = g4 * 8 + j;
                if ((r >> 4) == half)
                    Bf[u][kc][j] = (short)bf16bits(ws[(r & 15) * WS_STRIDE + col] * sc);
            }
        }
        __syncthreads();
    }

    const int dd = wv * 32 + (lane & 31);
    const float brh_l = gbias[K3H + 512 + dd] * LOG2E2;
    const int tsel = (lane >> 4) & 1;

    const float* xps = xp + (size_t)seq * SEQ * K3H;
    float* outs = out + (size_t)seq * SEQ * HID;

    float h = 0.f;
    if (tid < HID) hbf[0][tid] = 0;

    // prologue: DMA rows 0 and 1; full drain once
    if (wv < 3) {
        load_lds16(xps + wv * 256 + (lane << 2),       xq0 + wv * 256);
        load_lds16(xps + K3H + wv * 256 + (lane << 2), xq1 + wv * 256);
    }
    asm volatile("s_waitcnt vmcnt(0)" ::: "memory");
    __syncthreads();

    // rotating xq pointers: p0 = read(s), p1 = read(s+1), p2 = DMA target (s+2)
    float* p0 = xq0;
    float* p1 = xq1;
    float* p2 = xq2;

    // one GRU step; CB/NB are compile-time via unroll-2
    #define K4_STEP(s_, CB, NB)                                                         \
    {                                                                                   \
        const int sp = ((s_) + 2 < SEQ) ? (s_) + 2 : SEQ - 1;                           \
        if (wv < 3)                                                                     \
            load_lds16(xps + (size_t)sp * K3H + wv * 256 + (lane << 2), p2 + wv * 256); \
        short8 av[8];                                                                   \
        _Pragma("unroll")                                                               \
        for (int kc = 0; kc < 8; ++kc)                                                  \
            av[kc] = *reinterpret_cast<const short8*>(&hbf[CB][kc * 32 + g4 * 8]);      \
        const float xz = p0[dd];                                                        \
        const float xr = p0[256 + dd];                                                  \
        const float xh = p0[512 + dd];                                                  \
        floatx4 C[6];                                                                   \
        _Pragma("unroll")                                                               \
        for (int u = 0; u < 6; ++u) C[u] = (floatx4){0.f, 0.f, 0.f, 0.f};               \
        _Pragma("unroll")                                                               \
        for (int kc = 0; kc < 8; ++kc) {                                                \
            _Pragma("unroll")                                                           \
            for (int u = 0; u < 6; ++u)                                                 \
                C[u] = __builtin_amdgcn_mfma_f32_16x16x32_bf16(av[kc], Bf[u][kc],       \
                                                               C[u], 0, 0, 0);         \
        }                                                                               \
        if (lane < 32) {                                                                \
            float rz = tsel ? C[1][0] : C[0][0];                                        \
            float rr = tsel ? C[3][0] : C[2][0];                                        \
            float rh = tsel ? C[5][0] : C[4][0];                                        \
            float z  = frcp(1.f + __builtin_amdgcn_exp2f(-(rz + xz)));                  \
            float r  = frcp(1.f + __builtin_amdgcn_exp2f(-(rr + xr)));                  \
            float th = fmaf(r, rh + brh_l, xh);                                         \
            float hh = 1.f - 2.f * frcp(1.f + __builtin_amdgcn_exp2f(th));              \
            h = hh + z * (h - hh);                                                      \
            hbf[NB][dd] = bf16bits(h);                                                  \
            outs[(s_) * HID + dd] = h;                                                  \
        }                                                                               \
        asm volatile("s_waitcnt vmcnt(3) lgkmcnt(0)\n\ts_barrier" ::: "memory");        \
        float* tmp_ = p0; p0 = p1; p1 = p2; p2 = tmp_;                                  \
    }

    for (int s = 0; s < SEQ; s += 2) {
        K4_STEP(s,     0, 1)
        K4_STEP(s + 1, 1, 0)
    }
    #undef K4_STEP
}

extern "C" void kernel_launch(void* const* d_in, const int* in_sizes, int n_in,
                              void* d_out, int out_size, void* d_ws, size_t ws_size,
                              hipStream_t stream) {
    const float* feat = (const float*)d_in[0];
    const float* w1   = (const float*)d_in[1];
    const float* w2   = (const float*)d_in[2];
    const float* bias = (const float*)d_in[3];
    const float* v3   = (const float*)d_in[4];
    const float* gk   = (const float*)d_in[5];
    const float* grk  = (const float*)d_in[6];
    const float* gb   = (const float*)d_in[7];
    float* out = (float*)d_out;

    char* wsb = (char*)d_ws;
    float* left  = (float*)(wsb);
    float* right = (float*)(wsb + (size_t)2 * 1024 * 1024);
    float* cbuf  = (float*)(wsb + (size_t)4 * 1024 * 1024);
    float* xp    = (float*)(wsb + (size_t)6 * 1024 * 1024);

    k1_leftright<<<2048 / 8, 256, 0, stream>>>(feat, w1, w2, left, right);
    k2_attn<<<NSEQ * 32, 256, 0, stream>>>(feat, left, right, bias, v3, cbuf);
    k3_mfma<<<128, 512, 0, stream>>>(feat, cbuf, gk, gb, xp);
    k4_gru<<<NSEQ, 512, 0, stream>>>(grk, gb, xp, out);
}